// Round 1
// baseline (885.177 us; speedup 1.0000x reference)
//
#include <hip/hip_runtime.h>
#include <math.h>

#define N_NODES 512
#define SD_ 256
#define VD_ 128
#define ED_ 128
#define NE_ 262144
#define NG_ 16
#define NA_ 16
#define NB_ 5
#define TE 32

__device__ __forceinline__ float silu_f(float x) { return x / (1.0f + expf(-x)); }

// ---------------- Node phase: s2 = silu(s@W_sm+b_sm); atoms = s2@W_a+b_a; cpred = p + v@W_c
__global__ __launch_bounds__(256) void node_kernel(
    const float* __restrict__ s, const float* __restrict__ v, const float* __restrict__ p,
    const float* __restrict__ W_sm, const float* __restrict__ b_sm,
    const float* __restrict__ W_a, const float* __restrict__ b_a,
    const float* __restrict__ W_c,
    float* __restrict__ s2, float* __restrict__ cpred, float* __restrict__ atoms_out)
{
    const int node = blockIdx.x;
    const int tid  = threadIdx.x;
    __shared__ float srow[SD_];
    __shared__ float s2row[SD_];
    srow[tid] = s[(size_t)node * SD_ + tid];
    __syncthreads();
    float acc = b_sm[tid];
    #pragma unroll 8
    for (int c = 0; c < SD_; ++c) acc = fmaf(srow[c], W_sm[(size_t)c * SD_ + tid], acc);
    float sv = silu_f(acc);
    s2[(size_t)node * SD_ + tid] = sv;
    s2row[tid] = sv;
    __syncthreads();
    if (tid < NA_) {
        float a = b_a[tid];
        #pragma unroll 8
        for (int c = 0; c < SD_; ++c) a = fmaf(s2row[c], W_a[(size_t)c * NA_ + tid], a);
        atoms_out[(size_t)node * NA_ + tid] = a;
    } else if (tid >= 64 && tid < 67) {
        int dd = tid - 64;
        float a = p[node * 3 + dd];
        const float* vr = v + (size_t)(node * 3 + dd) * VD_;
        #pragma unroll 8
        for (int c = 0; c < VD_; ++c) a = fmaf(vr[c], W_c[c], a);
        cpred[node * 3 + dd] = a;
    }
}

// ---------------- Per-graph mean centering (deterministic serial segment sums)
__global__ __launch_bounds__(512) void center_kernel(
    const float* __restrict__ cpred, const int* __restrict__ batch,
    float* __restrict__ coords_ws, float* __restrict__ coords_out)
{
    __shared__ float cl[N_NODES * 3];
    __shared__ int   bl[N_NODES];
    __shared__ float meanv[NG_ * 3];
    const int tid = threadIdx.x;
    bl[tid] = batch[tid];
    #pragma unroll
    for (int dd = 0; dd < 3; ++dd) cl[tid * 3 + dd] = cpred[tid * 3 + dd];
    __syncthreads();
    if (tid < NG_ * 3) {
        int g = tid / 3, dd = tid % 3;
        float sum = 0.f; int cnt = 0;
        for (int n = 0; n < N_NODES; ++n) {
            if (bl[n] == g) { sum += cl[n * 3 + dd]; cnt++; }
        }
        meanv[tid] = sum / (float)(cnt > 0 ? cnt : 1);
    }
    __syncthreads();
    int g = bl[tid];
    #pragma unroll
    for (int dd = 0; dd < 3; ++dd) {
        float val = cl[tid * 3 + dd] - meanv[g * 3 + dd];
        coords_ws[tid * 3 + dd]  = val;
        coords_out[tid * 3 + dd] = val;
    }
}

// ---------------- last-wins scatter map: emap[j*512+i] = max k with (j_k,i_k)==(j,i)
__global__ __launch_bounds__(1024) void map_init(int* __restrict__ m)
{
    int idx = blockIdx.x * blockDim.x + threadIdx.x;
    m[idx] = -1;
}

__global__ __launch_bounds__(256) void map_build(const int* __restrict__ ei, int* __restrict__ m)
{
    int k = blockIdx.x * blockDim.x + threadIdx.x;
    int j = ei[k], i = ei[NE_ + k];
    atomicMax(&m[j * N_NODES + i], k);
}

// ---------------- Fused edge pipeline: e_sym -> f -> h -> bonds
__global__ __launch_bounds__(256) void edge_kernel(
    const float* __restrict__ e, const int* __restrict__ ei, const int* __restrict__ emap,
    const float* __restrict__ coords, const float* __restrict__ s2,
    const float* __restrict__ W_bm, const float* __restrict__ b_bm,
    const float* __restrict__ W_b0, const float* __restrict__ b_b0,
    const float* __restrict__ W_b1, const float* __restrict__ b_b1,
    float* __restrict__ bonds_out)
{
    __shared__ float esym[TE][ED_ + 4];
    __shared__ float fd[TE][SD_ + 4];   // cols 0..255 = f, col 256 = d
    __shared__ int li[TE], lj[TE], lk1[TE], lk2[TE];

    const int tid = threadIdx.x;
    const int ebase = blockIdx.x * TE;

    if (tid < TE) {
        int k = ebase + tid;
        int j = ei[k], i = ei[NE_ + k];
        li[tid] = i; lj[tid] = j;
        lk1[tid] = emap[j * N_NODES + i];
        lk2[tid] = emap[i * N_NODES + j];
        float dx = coords[i * 3 + 0] - coords[j * 3 + 0];
        float dy = coords[i * 3 + 1] - coords[j * 3 + 1];
        float dz = coords[i * 3 + 2] - coords[j * 3 + 2];
        fd[tid][SD_] = dx * dx + dy * dy + dz * dz;
    }
    __syncthreads();

    // gather + symmetrize e: 8 threads per edge row, 16 floats each
    {
        int t  = tid >> 3;
        int c0 = (tid & 7) * 16;
        const float4* p1 = reinterpret_cast<const float4*>(e + (size_t)lk1[t] * ED_ + c0);
        float4 a[4] = { p1[0], p1[1], p1[2], p1[3] };
        int k2 = lk2[t];
        if (k2 >= 0) {
            const float4* p2 = reinterpret_cast<const float4*>(e + (size_t)k2 * ED_ + c0);
            #pragma unroll
            for (int q = 0; q < 4; ++q) {
                float4 b = p2[q];
                a[q].x += b.x; a[q].y += b.y; a[q].z += b.z; a[q].w += b.w;
            }
        }
        #pragma unroll
        for (int q = 0; q < 4; ++q) {
            esym[t][c0 + q * 4 + 0] = 0.5f * a[q].x;
            esym[t][c0 + q * 4 + 1] = 0.5f * a[q].y;
            esym[t][c0 + q * 4 + 2] = 0.5f * a[q].z;
            esym[t][c0 + q * 4 + 3] = 0.5f * a[q].w;
        }
    }
    __syncthreads();

    const int oc = tid & 31;         // 32 column-groups of 8 outputs
    const int eg = tid >> 5;         // 8 edge-groups of 4 edges
    const int o0 = oc * 8;
    const int t0 = eg * 4;

    // GEMM1: f = s_i + s_j + b_bm + esym @ W_bm   (K=128)
    float acc[4][8];
    #pragma unroll
    for (int ee = 0; ee < 4; ++ee) {
        const float* si = s2 + (size_t)li[t0 + ee] * SD_ + o0;
        const float* sj = s2 + (size_t)lj[t0 + ee] * SD_ + o0;
        #pragma unroll
        for (int oo = 0; oo < 8; ++oo) acc[ee][oo] = si[oo] + sj[oo] + b_bm[o0 + oo];
    }
    {
        const float* wp = W_bm + o0;
        #pragma unroll 4
        for (int c = 0; c < ED_; ++c) {
            const float4 w0 = *reinterpret_cast<const float4*>(wp);
            const float4 w1 = *reinterpret_cast<const float4*>(wp + 4);
            wp += SD_;
            float ev[4];
            #pragma unroll
            for (int ee = 0; ee < 4; ++ee) ev[ee] = esym[t0 + ee][c];
            #pragma unroll
            for (int ee = 0; ee < 4; ++ee) {
                acc[ee][0] = fmaf(ev[ee], w0.x, acc[ee][0]);
                acc[ee][1] = fmaf(ev[ee], w0.y, acc[ee][1]);
                acc[ee][2] = fmaf(ev[ee], w0.z, acc[ee][2]);
                acc[ee][3] = fmaf(ev[ee], w0.w, acc[ee][3]);
                acc[ee][4] = fmaf(ev[ee], w1.x, acc[ee][4]);
                acc[ee][5] = fmaf(ev[ee], w1.y, acc[ee][5]);
                acc[ee][6] = fmaf(ev[ee], w1.z, acc[ee][6]);
                acc[ee][7] = fmaf(ev[ee], w1.w, acc[ee][7]);
            }
        }
    }
    #pragma unroll
    for (int ee = 0; ee < 4; ++ee)
        #pragma unroll
        for (int oo = 0; oo < 8; ++oo) fd[t0 + ee][o0 + oo] = acc[ee][oo];
    __syncthreads();

    // GEMM2: pre = [f, d] @ W_b0 + b_b0   (K=257)
    float acc2[4][8];
    #pragma unroll
    for (int ee = 0; ee < 4; ++ee)
        #pragma unroll
        for (int oo = 0; oo < 8; ++oo) acc2[ee][oo] = b_b0[o0 + oo];
    {
        const float* wp = W_b0 + o0;
        #pragma unroll 4
        for (int c = 0; c <= SD_; ++c) {   // 257 iterations
            const float4 w0 = *reinterpret_cast<const float4*>(wp);
            const float4 w1 = *reinterpret_cast<const float4*>(wp + 4);
            wp += SD_;
            float fv[4];
            #pragma unroll
            for (int ee = 0; ee < 4; ++ee) fv[ee] = fd[t0 + ee][c];
            #pragma unroll
            for (int ee = 0; ee < 4; ++ee) {
                acc2[ee][0] = fmaf(fv[ee], w0.x, acc2[ee][0]);
                acc2[ee][1] = fmaf(fv[ee], w0.y, acc2[ee][1]);
                acc2[ee][2] = fmaf(fv[ee], w0.z, acc2[ee][2]);
                acc2[ee][3] = fmaf(fv[ee], w0.w, acc2[ee][3]);
                acc2[ee][4] = fmaf(fv[ee], w1.x, acc2[ee][4]);
                acc2[ee][5] = fmaf(fv[ee], w1.y, acc2[ee][5]);
                acc2[ee][6] = fmaf(fv[ee], w1.z, acc2[ee][6]);
                acc2[ee][7] = fmaf(fv[ee], w1.w, acc2[ee][7]);
            }
        }
    }

    // silu + bonds partials + cross-lane reduce (over the 32 oc-lanes)
    float pb[4][NB_];
    #pragma unroll
    for (int ee = 0; ee < 4; ++ee)
        #pragma unroll
        for (int b = 0; b < NB_; ++b) pb[ee][b] = 0.f;
    #pragma unroll
    for (int ee = 0; ee < 4; ++ee) {
        #pragma unroll
        for (int oo = 0; oo < 8; ++oo) {
            float h = silu_f(acc2[ee][oo]);
            #pragma unroll
            for (int b = 0; b < NB_; ++b)
                pb[ee][b] = fmaf(h, W_b1[(size_t)(o0 + oo) * NB_ + b], pb[ee][b]);
        }
    }
    for (int off = 16; off > 0; off >>= 1) {
        #pragma unroll
        for (int ee = 0; ee < 4; ++ee)
            #pragma unroll
            for (int b = 0; b < NB_; ++b)
                pb[ee][b] += __shfl_xor(pb[ee][b], off);
    }
    if (oc == 0) {
        #pragma unroll
        for (int ee = 0; ee < 4; ++ee)
            #pragma unroll
            for (int b = 0; b < NB_; ++b)
                bonds_out[(size_t)(ebase + t0 + ee) * NB_ + b] = pb[ee][b] + b_b1[b];
    }
}

extern "C" void kernel_launch(void* const* d_in, const int* in_sizes, int n_in,
                              void* d_out, int out_size, void* d_ws, size_t ws_size,
                              hipStream_t stream)
{
    const float* s    = (const float*)d_in[0];
    const float* v    = (const float*)d_in[1];
    const float* p    = (const float*)d_in[2];
    const float* e    = (const float*)d_in[3];
    const int*   batch= (const int*)d_in[4];
    const int*   ei   = (const int*)d_in[5];
    const float* W_sm = (const float*)d_in[6];
    const float* b_sm = (const float*)d_in[7];
    const float* W_bm = (const float*)d_in[8];
    const float* b_bm = (const float*)d_in[9];
    const float* W_b0 = (const float*)d_in[10];
    const float* b_b0 = (const float*)d_in[11];
    const float* W_b1 = (const float*)d_in[12];
    const float* b_b1 = (const float*)d_in[13];
    const float* W_c  = (const float*)d_in[14];
    const float* W_a  = (const float*)d_in[15];
    const float* b_a  = (const float*)d_in[16];

    float* out = (float*)d_out;
    float* coords_out = out;                       // 512*3
    float* atoms_out  = out + 1536;                // 512*16
    float* bonds_out  = out + 1536 + 8192;         // 262144*5

    char* ws = (char*)d_ws;
    int*   emap   = (int*)ws;                                       // 1 MB
    float* s2     = (float*)(ws + (1 << 20));                       // 512 KB
    float* cpred  = (float*)(ws + (1 << 20) + 512 * 1024);          // 6 KB
    float* coords = cpred + N_NODES * 3;                            // 6 KB

    node_kernel<<<N_NODES, 256, 0, stream>>>(s, v, p, W_sm, b_sm, W_a, b_a, W_c,
                                             s2, cpred, atoms_out);
    center_kernel<<<1, 512, 0, stream>>>(cpred, batch, coords, coords_out);
    map_init<<<(N_NODES * N_NODES) / 1024, 1024, 0, stream>>>(emap);
    map_build<<<NE_ / 256, 256, 0, stream>>>(ei, emap);
    edge_kernel<<<NE_ / TE, 256, 0, stream>>>(e, ei, emap, coords, s2,
                                              W_bm, b_bm, W_b0, b_b0, W_b1, b_b1,
                                              bonds_out);
}

// Round 2
// 239.271 us; speedup vs baseline: 3.6995x; 3.6995x over previous
//
#include <hip/hip_runtime.h>
#include <math.h>

#define N_NODES 512
#define SD_ 256
#define VD_ 128
#define ED_ 128
#define NE_ 262144
#define NG_ 16
#define NA_ 16
#define NB_ 5

typedef __attribute__((ext_vector_type(8))) short bf16x8;
typedef __attribute__((ext_vector_type(4))) float f32x4;

__device__ __forceinline__ float silu_f(float x) { return x / (1.0f + expf(-x)); }
__device__ __forceinline__ float silu_fast(float x) {
    return x * __builtin_amdgcn_rcpf(1.0f + __builtin_amdgcn_exp2f(x * -1.44269504f));
}
__device__ __forceinline__ unsigned short f2bf(float x) {
    unsigned int u = __float_as_uint(x);
    return (unsigned short)((u + 0x7fffu + ((u >> 16) & 1u)) >> 16);
}
__device__ __forceinline__ float bf2f(unsigned short h) {
    return __uint_as_float(((unsigned int)h) << 16);
}
__device__ __forceinline__ unsigned int cvt_pk_bf16(float lo, float hi) {
    unsigned int r;
    asm("v_cvt_pk_bf16_f32 %0, %1, %2" : "=v"(r) : "v"(lo), "v"(hi));
    return r;
}

// ---------------- Node phase: s2b = bf16(silu(s@W_sm+b_sm)); atoms = s2@W_a+b_a; cpred = p + v@W_c
__global__ __launch_bounds__(256) void node_kernel(
    const float* __restrict__ s, const float* __restrict__ v, const float* __restrict__ p,
    const float* __restrict__ W_sm, const float* __restrict__ b_sm,
    const float* __restrict__ W_a, const float* __restrict__ b_a,
    const float* __restrict__ W_c,
    unsigned short* __restrict__ s2b, float* __restrict__ cpred, float* __restrict__ atoms_out)
{
    const int node = blockIdx.x;
    const int tid  = threadIdx.x;
    __shared__ float srow[SD_];
    __shared__ float s2row[SD_];
    srow[tid] = s[(size_t)node * SD_ + tid];
    __syncthreads();
    float acc = b_sm[tid];
    #pragma unroll 8
    for (int c = 0; c < SD_; ++c) acc = fmaf(srow[c], W_sm[(size_t)c * SD_ + tid], acc);
    float sv = silu_f(acc);
    s2b[(size_t)node * SD_ + tid] = f2bf(sv);
    s2row[tid] = sv;
    __syncthreads();
    if (tid < NA_) {
        float a = b_a[tid];
        #pragma unroll 8
        for (int c = 0; c < SD_; ++c) a = fmaf(s2row[c], W_a[(size_t)c * NA_ + tid], a);
        atoms_out[(size_t)node * NA_ + tid] = a;
    } else if (tid >= 64 && tid < 67) {
        int dd = tid - 64;
        float a = p[node * 3 + dd];
        const float* vr = v + (size_t)(node * 3 + dd) * VD_;
        #pragma unroll 8
        for (int c = 0; c < VD_; ++c) a = fmaf(vr[c], W_c[c], a);
        cpred[node * 3 + dd] = a;
    }
}

// ---------------- Per-graph mean centering (deterministic serial segment sums)
__global__ __launch_bounds__(512) void center_kernel(
    const float* __restrict__ cpred, const int* __restrict__ batch,
    float* __restrict__ coords_ws, float* __restrict__ coords_out)
{
    __shared__ float cl[N_NODES * 3];
    __shared__ int   bl[N_NODES];
    __shared__ float meanv[NG_ * 3];
    const int tid = threadIdx.x;
    bl[tid] = batch[tid];
    #pragma unroll
    for (int dd = 0; dd < 3; ++dd) cl[tid * 3 + dd] = cpred[tid * 3 + dd];
    __syncthreads();
    if (tid < NG_ * 3) {
        int g = tid / 3, dd = tid % 3;
        float sum = 0.f; int cnt = 0;
        for (int n = 0; n < N_NODES; ++n) {
            if (bl[n] == g) { sum += cl[n * 3 + dd]; cnt++; }
        }
        meanv[tid] = sum / (float)(cnt > 0 ? cnt : 1);
    }
    __syncthreads();
    int g = bl[tid];
    #pragma unroll
    for (int dd = 0; dd < 3; ++dd) {
        float val = cl[tid * 3 + dd] - meanv[g * 3 + dd];
        coords_ws[tid * 3 + dd]  = val;
        coords_out[tid * 3 + dd] = val;
    }
}

// ---------------- last-wins scatter map
__global__ __launch_bounds__(1024) void map_init(int* __restrict__ m)
{
    int idx = blockIdx.x * blockDim.x + threadIdx.x;
    m[idx] = -1;
}

__global__ __launch_bounds__(256) void map_build(const int* __restrict__ ei, int* __restrict__ m)
{
    int k = blockIdx.x * blockDim.x + threadIdx.x;
    int j = ei[k], i = ei[NE_ + k];
    atomicMax(&m[j * N_NODES + i], k);
}

// ---------------- pack W^T slices into MFMA A-fragment order (bf16)
// out[idx*8 + i] = W[k, m] with m = mtg*16 + (l&15), k = kb*32 + (l>>4)*8 + i
// idx = (mtg*nkb + kb)*64 + l
__global__ __launch_bounds__(256) void pack_wA(
    const float* __restrict__ W, unsigned short* __restrict__ out,
    int nkb, int stride, int Mreal, int total)
{
    int idx = blockIdx.x * 256 + threadIdx.x;
    if (idx >= total) return;
    int l = idx & 63;
    int kb = (idx >> 6) % nkb;
    int mtg = idx / (64 * nkb);
    int m = mtg * 16 + (l & 15);
    int k0 = kb * 32 + (l >> 4) * 8;
    unsigned short vv[8];
    #pragma unroll
    for (int i = 0; i < 8; ++i) {
        float x = (m < Mreal) ? W[(size_t)(k0 + i) * stride + m] : 0.0f;
        vv[i] = f2bf(x);
    }
    bf16x8 pack;
    #pragma unroll
    for (int i = 0; i < 8; ++i) pack[i] = (short)vv[i];
    *(bf16x8*)(out + (size_t)idx * 8) = pack;
}

// ---------------- Fused edge pipeline, MFMA version
// Block = 64 edges, 4 waves. Wave w owns output columns [w*64, w*64+64).
// GEMM1': f^T = W_bm^T @ esym^T (+ s_i + s_j + b_bm in epilogue)
// GEMM2': pre^T = W_b0^T @ f^T (+ b_b0 + d*W_b0[256] in init)
// GEMM3': bonds^T = W_b1p^T @ h^T (+ b_b1 in epilogue)
__global__ __launch_bounds__(256) void edge_mfma(
    const float* __restrict__ e, const int* __restrict__ ei, const int* __restrict__ emap,
    const float* __restrict__ coords, const unsigned short* __restrict__ s2b,
    const unsigned short* __restrict__ WfA_bm, const unsigned short* __restrict__ WfA_b0,
    const unsigned short* __restrict__ WfA_b1,
    const float* __restrict__ b_bm, const float* __restrict__ W_b0_last,
    const float* __restrict__ b_b0, const float* __restrict__ b_b1,
    float* __restrict__ bonds_out)
{
    __shared__ unsigned short esym_lds[64 * 128];   // 16 KB, B-fragment chunk order
    __shared__ unsigned short fd_lds[64 * 256];     // 32 KB, XOR-swizzled [edge][col]
    __shared__ float dw[64];
    __shared__ int li_s[64], lj_s[64], lk1s[64], lk2s[64];

    const int tid = threadIdx.x;
    const int blk = blockIdx.x;
    const int l   = tid & 63;
    const int w   = tid >> 6;
    const int eLo = l & 15;
    const int hi  = l >> 4;

    // ---- phase A: per-edge metadata
    if (tid < 64) {
        int ge = blk * 64 + tid;
        int j = ei[ge], i2 = ei[NE_ + ge];
        li_s[tid] = i2; lj_s[tid] = j;
        lk1s[tid] = emap[j * N_NODES + i2];
        lk2s[tid] = emap[i2 * N_NODES + j];
        float dx = coords[i2 * 3 + 0] - coords[j * 3 + 0];
        float dy = coords[i2 * 3 + 1] - coords[j * 3 + 1];
        float dz = coords[i2 * 3 + 2] - coords[j * 3 + 2];
        dw[tid] = dx * dx + dy * dy + dz * dz;
    }
    __syncthreads();

    // ---- phase B: gather + symmetrize e into LDS B-fragment layout (bf16)
    {
        int eL = tid >> 2;          // edge-local 0..63
        int q  = tid & 3;           // k-block 0..3 (32 k each)
        int k1 = lk1s[eL], k2 = lk2s[eL];
        const float4* p1 = (const float4*)(e + (size_t)k1 * ED_ + q * 32);
        float4 va[8];
        #pragma unroll
        for (int t = 0; t < 8; ++t) va[t] = p1[t];
        if (k2 >= 0) {
            const float4* p2 = (const float4*)(e + (size_t)k2 * ED_ + q * 32);
            #pragma unroll
            for (int t = 0; t < 8; ++t) {
                float4 b4 = p2[t];
                va[t].x += b4.x; va[t].y += b4.y; va[t].z += b4.z; va[t].w += b4.w;
            }
        }
        int ntB = eL >> 4, eLoB = eL & 15;
        #pragma unroll
        for (int h2 = 0; h2 < 4; ++h2) {
            float4 x0 = va[h2 * 2], x1 = va[h2 * 2 + 1];
            uint4 c;
            c.x = cvt_pk_bf16(0.5f * x0.x, 0.5f * x0.y);
            c.y = cvt_pk_bf16(0.5f * x0.z, 0.5f * x0.w);
            c.z = cvt_pk_bf16(0.5f * x1.x, 0.5f * x1.y);
            c.w = cvt_pk_bf16(0.5f * x1.z, 0.5f * x1.w);
            int chunk = ((ntB * 4 + q) * 64 + h2 * 16 + eLoB);
            *(uint4*)(&esym_lds[chunk * 8]) = c;
        }
    }
    __syncthreads();

    // ---- GEMM1': acc[mt][nt], K=128 (4 k-steps)
    f32x4 acc[4][4];
    #pragma unroll
    for (int mt = 0; mt < 4; ++mt)
        #pragma unroll
        for (int nt = 0; nt < 4; ++nt) acc[mt][nt] = (f32x4){0.f, 0.f, 0.f, 0.f};

    #pragma unroll
    for (int kb = 0; kb < 4; ++kb) {
        bf16x8 af[4], bfg[4];
        #pragma unroll
        for (int mt = 0; mt < 4; ++mt)
            af[mt] = *(const bf16x8*)(WfA_bm + ((((w * 4 + mt) * 4 + kb) << 6 | l) << 3));
        #pragma unroll
        for (int nt = 0; nt < 4; ++nt)
            bfg[nt] = *(const bf16x8*)(&esym_lds[(((nt * 4 + kb) << 6) | l) << 3]);
        #pragma unroll
        for (int mt = 0; mt < 4; ++mt)
            #pragma unroll
            for (int nt = 0; nt < 4; ++nt)
                acc[mt][nt] = __builtin_amdgcn_mfma_f32_16x16x32_bf16(af[mt], bfg[nt], acc[mt][nt], 0, 0, 0);
    }

    // ---- epilogue 1: f = acc + s_i + s_j + b_bm -> swizzled LDS (bf16)
    #pragma unroll
    for (int mt = 0; mt < 4; ++mt) {
        int m0 = w * 64 + mt * 16 + hi * 4;
        float4 bb = *(const float4*)(b_bm + m0);
        #pragma unroll
        for (int nt = 0; nt < 4; ++nt) {
            int edge = nt * 16 + eLo;
            int ni = li_s[edge], nj = lj_s[edge];
            ushort4 si = *(const ushort4*)(s2b + ni * SD_ + m0);
            ushort4 sj = *(const ushort4*)(s2b + nj * SD_ + m0);
            f32x4 r = acc[mt][nt];
            float f0 = r[0] + bf2f(si.x) + bf2f(sj.x) + bb.x;
            float f1 = r[1] + bf2f(si.y) + bf2f(sj.y) + bb.y;
            float f2 = r[2] + bf2f(si.z) + bf2f(sj.z) + bb.z;
            float f3 = r[3] + bf2f(si.w) + bf2f(sj.w) + bb.w;
            uint2 pk;
            pk.x = cvt_pk_bf16(f0, f1);
            pk.y = cvt_pk_bf16(f2, f3);
            int c16 = m0 >> 3;
            int byteo = (edge << 9) + (((c16 ^ ((edge & 7) << 2)) << 4)) + ((m0 & 7) << 1);
            *(uint2*)((char*)fd_lds + byteo) = pk;
        }
    }
    __syncthreads();

    // ---- GEMM2': K=256 (8 k-steps); init = b_b0 + d * W_b0[row 256]
    #pragma unroll
    for (int mt = 0; mt < 4; ++mt) {
        int m0 = w * 64 + mt * 16 + hi * 4;
        float4 b0 = *(const float4*)(b_b0 + m0);
        float4 w2 = *(const float4*)(W_b0_last + m0);
        #pragma unroll
        for (int nt = 0; nt < 4; ++nt) {
            int edge = nt * 16 + eLo;
            float dd = dw[edge];
            acc[mt][nt] = (f32x4){fmaf(dd, w2.x, b0.x), fmaf(dd, w2.y, b0.y),
                                  fmaf(dd, w2.z, b0.z), fmaf(dd, w2.w, b0.w)};
        }
    }
    #pragma unroll
    for (int kb = 0; kb < 8; ++kb) {
        bf16x8 af[4], bfg[4];
        #pragma unroll
        for (int mt = 0; mt < 4; ++mt)
            af[mt] = *(const bf16x8*)(WfA_b0 + ((((w * 4 + mt) * 8 + kb) << 6 | l) << 3));
        #pragma unroll
        for (int nt = 0; nt < 4; ++nt) {
            int edge = nt * 16 + eLo;
            int c16 = (kb << 2) + hi;
            int byteo = (edge << 9) + ((c16 ^ ((edge & 7) << 2)) << 4);
            bfg[nt] = *(const bf16x8*)((const char*)fd_lds + byteo);
        }
        #pragma unroll
        for (int mt = 0; mt < 4; ++mt)
            #pragma unroll
            for (int nt = 0; nt < 4; ++nt)
                acc[mt][nt] = __builtin_amdgcn_mfma_f32_16x16x32_bf16(af[mt], bfg[nt], acc[mt][nt], 0, 0, 0);
    }
    __syncthreads();   // all GEMM2 reads of fd done before h overwrites it

    // ---- epilogue 2: h = silu(pre) -> swizzled LDS (bf16)
    #pragma unroll
    for (int mt = 0; mt < 4; ++mt) {
        int m0 = w * 64 + mt * 16 + hi * 4;
        #pragma unroll
        for (int nt = 0; nt < 4; ++nt) {
            int edge = nt * 16 + eLo;
            f32x4 r = acc[mt][nt];
            float h0 = silu_fast(r[0]);
            float h1 = silu_fast(r[1]);
            float h2 = silu_fast(r[2]);
            float h3 = silu_fast(r[3]);
            uint2 pk;
            pk.x = cvt_pk_bf16(h0, h1);
            pk.y = cvt_pk_bf16(h2, h3);
            int c16 = m0 >> 3;
            int byteo = (edge << 9) + ((c16 ^ ((edge & 7) << 2)) << 4) + ((m0 & 7) << 1);
            *(uint2*)((char*)fd_lds + byteo) = pk;
        }
    }
    __syncthreads();

    // ---- GEMM3': bonds (wave w handles edges w*16..w*16+15)
    f32x4 acc3 = (f32x4){0.f, 0.f, 0.f, 0.f};
    #pragma unroll
    for (int kb = 0; kb < 8; ++kb) {
        bf16x8 af = *(const bf16x8*)(WfA_b1 + ((kb << 6 | l) << 3));
        int edge = (w << 4) + eLo;
        int c16 = (kb << 2) + hi;
        int byteo = (edge << 9) + ((c16 ^ ((edge & 7) << 2)) << 4);
        bf16x8 bfg = *(const bf16x8*)((const char*)fd_lds + byteo);
        acc3 = __builtin_amdgcn_mfma_f32_16x16x32_bf16(af, bfg, acc3, 0, 0, 0);
    }
    {
        int ge = blk * 64 + (w << 4) + eLo;
        if (hi == 0) {
            bonds_out[(size_t)ge * NB_ + 0] = acc3[0] + b_b1[0];
            bonds_out[(size_t)ge * NB_ + 1] = acc3[1] + b_b1[1];
            bonds_out[(size_t)ge * NB_ + 2] = acc3[2] + b_b1[2];
            bonds_out[(size_t)ge * NB_ + 3] = acc3[3] + b_b1[3];
        } else if (hi == 1) {
            bonds_out[(size_t)ge * NB_ + 4] = acc3[0] + b_b1[4];
        }
    }
}

extern "C" void kernel_launch(void* const* d_in, const int* in_sizes, int n_in,
                              void* d_out, int out_size, void* d_ws, size_t ws_size,
                              hipStream_t stream)
{
    const float* s    = (const float*)d_in[0];
    const float* v    = (const float*)d_in[1];
    const float* p    = (const float*)d_in[2];
    const float* e    = (const float*)d_in[3];
    const int*   batch= (const int*)d_in[4];
    const int*   ei   = (const int*)d_in[5];
    const float* W_sm = (const float*)d_in[6];
    const float* b_sm = (const float*)d_in[7];
    const float* W_bm = (const float*)d_in[8];
    const float* b_bm = (const float*)d_in[9];
    const float* W_b0 = (const float*)d_in[10];
    const float* b_b0 = (const float*)d_in[11];
    const float* W_b1 = (const float*)d_in[12];
    const float* b_b1 = (const float*)d_in[13];
    const float* W_c  = (const float*)d_in[14];
    const float* W_a  = (const float*)d_in[15];
    const float* b_a  = (const float*)d_in[16];

    float* out = (float*)d_out;
    float* coords_out = out;                       // 512*3
    float* atoms_out  = out + 1536;                // 512*16
    float* bonds_out  = out + 1536 + 8192;         // 262144*5

    char* ws = (char*)d_ws;
    int*            emap    = (int*)ws;                                  // @0, 1 MB
    unsigned short* s2b     = (unsigned short*)(ws + 0x100000);          // 256 KB
    unsigned short* WfA_bm  = (unsigned short*)(ws + 0x140000);          // 64 KB
    unsigned short* WfA_b0  = (unsigned short*)(ws + 0x150000);          // 128 KB
    unsigned short* WfA_b1  = (unsigned short*)(ws + 0x170000);          // 8 KB
    float*          cpred   = (float*)(ws + 0x172000);                   // 6 KB
    float*          coords  = (float*)(ws + 0x174000);                   // 6 KB

    map_init<<<(N_NODES * N_NODES) / 1024, 1024, 0, stream>>>(emap);
    map_build<<<NE_ / 256, 256, 0, stream>>>(ei, emap);
    node_kernel<<<N_NODES, 256, 0, stream>>>(s, v, p, W_sm, b_sm, W_a, b_a, W_c,
                                             s2b, cpred, atoms_out);
    center_kernel<<<1, 512, 0, stream>>>(cpred, batch, coords, coords_out);
    pack_wA<<<16, 256, 0, stream>>>(W_bm, WfA_bm, 4, SD_, SD_, 16 * 4 * 64);
    pack_wA<<<32, 256, 0, stream>>>(W_b0, WfA_b0, 8, SD_, SD_, 16 * 8 * 64);
    pack_wA<<<2, 256, 0, stream>>>(W_b1, WfA_b1, 8, NB_, NB_, 1 * 8 * 64);

    edge_mfma<<<NE_ / 64, 256, 0, stream>>>(e, ei, emap, coords, s2b,
                                            WfA_bm, WfA_b0, WfA_b1,
                                            b_bm, W_b0 + 256 * SD_, b_b0, b_b1,
                                            bonds_out);
}

// Round 4
// 235.505 us; speedup vs baseline: 3.7586x; 1.0160x over previous
//
#include <hip/hip_runtime.h>
#include <math.h>

#define N_NODES 512
#define SD_ 256
#define VD_ 128
#define ED_ 128
#define NE_ 262144
#define NG_ 16
#define NA_ 16
#define NB_ 5

typedef __attribute__((ext_vector_type(8))) short bf16x8;
typedef __attribute__((ext_vector_type(4))) float f32x4;

__device__ __forceinline__ float silu_f(float x) { return x / (1.0f + expf(-x)); }
__device__ __forceinline__ float silu_fast(float x) {
    return x * __builtin_amdgcn_rcpf(1.0f + __builtin_amdgcn_exp2f(x * -1.44269504f));
}
__device__ __forceinline__ unsigned short f2bf(float x) {
    unsigned int u = __float_as_uint(x);
    return (unsigned short)((u + 0x7fffu + ((u >> 16) & 1u)) >> 16);
}
__device__ __forceinline__ float bf2f(unsigned short h) {
    return __uint_as_float(((unsigned int)h) << 16);
}
__device__ __forceinline__ unsigned int cvt_pk_bf16(float lo, float hi) {
    unsigned int r;
    asm("v_cvt_pk_bf16_f32 %0, %1, %2" : "=v"(r) : "v"(lo), "v"(hi));
    return r;
}

// ---------------- Node phase: 8 nodes per block (W_sm read amortized 8x)
__global__ __launch_bounds__(256) void node_kernel8(
    const float* __restrict__ s, const float* __restrict__ v, const float* __restrict__ p,
    const float* __restrict__ W_sm, const float* __restrict__ b_sm,
    const float* __restrict__ W_a, const float* __restrict__ b_a,
    const float* __restrict__ W_c,
    unsigned short* __restrict__ s2b, float* __restrict__ cpred, float* __restrict__ atoms_out)
{
    const int n0  = blockIdx.x * 8;
    const int tid = threadIdx.x;
    __shared__ float srow[8][SD_];
    __shared__ float s2row[8][SD_];
    #pragma unroll
    for (int n = 0; n < 8; ++n) srow[n][tid] = s[(size_t)(n0 + n) * SD_ + tid];
    __syncthreads();
    float acc[8];
    {
        float bb = b_sm[tid];
        #pragma unroll
        for (int n = 0; n < 8; ++n) acc[n] = bb;
    }
    #pragma unroll 4
    for (int c = 0; c < SD_; ++c) {
        float wv = W_sm[(size_t)c * SD_ + tid];
        #pragma unroll
        for (int n = 0; n < 8; ++n) acc[n] = fmaf(srow[n][c], wv, acc[n]);
    }
    #pragma unroll
    for (int n = 0; n < 8; ++n) {
        float sv = silu_f(acc[n]);
        s2b[(size_t)(n0 + n) * SD_ + tid] = f2bf(sv);
        s2row[n][tid] = sv;
    }
    __syncthreads();
    if (tid < 128) {
        int n = tid >> 4, a = tid & 15;
        float x = b_a[a];
        #pragma unroll 8
        for (int c = 0; c < SD_; ++c) x = fmaf(s2row[n][c], W_a[(size_t)c * NA_ + a], x);
        atoms_out[(size_t)(n0 + n) * NA_ + a] = x;
    } else if (tid < 152) {
        int t = tid - 128;
        int n = t / 3, dd = t % 3;
        float x = p[(n0 + n) * 3 + dd];
        const float* vr = v + (size_t)((n0 + n) * 3 + dd) * VD_;
        #pragma unroll 8
        for (int c = 0; c < VD_; ++c) x = fmaf(vr[c], W_c[c], x);
        cpred[(n0 + n) * 3 + dd] = x;
    }
}

// ---------------- Per-graph mean centering (deterministic serial segment sums)
__global__ __launch_bounds__(512) void center_kernel(
    const float* __restrict__ cpred, const int* __restrict__ batch,
    float* __restrict__ coords_ws, float* __restrict__ coords_out)
{
    __shared__ float cl[N_NODES * 3];
    __shared__ int   bl[N_NODES];
    __shared__ float meanv[NG_ * 3];
    const int tid = threadIdx.x;
    bl[tid] = batch[tid];
    #pragma unroll
    for (int dd = 0; dd < 3; ++dd) cl[tid * 3 + dd] = cpred[tid * 3 + dd];
    __syncthreads();
    if (tid < NG_ * 3) {
        int g = tid / 3, dd = tid % 3;
        float sum = 0.f; int cnt = 0;
        for (int n = 0; n < N_NODES; ++n) {
            if (bl[n] == g) { sum += cl[n * 3 + dd]; cnt++; }
        }
        meanv[tid] = sum / (float)(cnt > 0 ? cnt : 1);
    }
    __syncthreads();
    int g = bl[tid];
    #pragma unroll
    for (int dd = 0; dd < 3; ++dd) {
        float val = cl[tid * 3 + dd] - meanv[g * 3 + dd];
        coords_ws[tid * 3 + dd]  = val;
        coords_out[tid * 3 + dd] = val;
    }
}

// ---------------- fused: last-wins map build (blocks 0..1023) + weight packing (blocks 1024..)
// pack: out[idx*8+i] = W[kb*32+(l>>4)*8+i, mtg*16+(l&15)], idx=(mtg*nkb+kb)*64+l
__device__ __forceinline__ void pack_one(
    const float* __restrict__ W, unsigned short* __restrict__ out, int nkb, int idx)
{
    int l = idx & 63;
    int kb = (idx >> 6) % nkb;
    int mtg = idx / (64 * nkb);
    int m = mtg * 16 + (l & 15);
    int k0 = kb * 32 + (l >> 4) * 8;
    bf16x8 pack;
    #pragma unroll
    for (int i = 0; i < 8; ++i) pack[i] = (short)f2bf(W[(size_t)(k0 + i) * SD_ + m]);
    *(bf16x8*)(out + (size_t)idx * 8) = pack;
}

__global__ __launch_bounds__(256) void build_and_pack(
    const int* __restrict__ ei, int* __restrict__ m,
    const float* __restrict__ W_bm, const float* __restrict__ W_b0,
    unsigned short* __restrict__ WfA_bm, unsigned short* __restrict__ WfA_b0)
{
    int bid = blockIdx.x;
    int tid = threadIdx.x;
    if (bid < NE_ / 256) {
        int k = bid * 256 + tid;
        int j = ei[k], i = ei[NE_ + k];
        atomicMax(&m[j * N_NODES + i], k);
    } else {
        int idx = (bid - NE_ / 256) * 256 + tid;   // 0..12287
        if (idx < 4096)  pack_one(W_bm, WfA_bm, 4, idx);
        else             pack_one(W_b0, WfA_b0, 8, idx - 4096);
    }
}

// ---------------- Fused edge pipeline, MFMA version (conflict-free LDS, 3 barriers)
// Block = 64 edges, 4 waves. Wave w owns output cols [w*64, w*64+64).
// GEMM1': f^T = W_bm^T @ esym^T (+ s_i + s_j + b_bm epilogue)
// GEMM2': pre^T = W_b0^T @ f^T (+ b_b0 + d*W_b0[256] init)
// bonds: VALU dot from GEMM2 acc (fp32 h), cross-lane + LDS reduce
__global__ __launch_bounds__(256) void edge_mfma(
    const float* __restrict__ e, const int* __restrict__ ei, const int* __restrict__ emap,
    const float* __restrict__ coords, const unsigned short* __restrict__ s2b,
    const unsigned short* __restrict__ WfA_bm, const unsigned short* __restrict__ WfA_b0,
    const float* __restrict__ W_b1,
    const float* __restrict__ b_bm, const float* __restrict__ W_b0_last,
    const float* __restrict__ b_b0, const float* __restrict__ b_b1,
    float* __restrict__ bonds_out)
{
    __shared__ __align__(16) char smem0[64 * 128 * 2];   // esym (16KB)  UNION  bonds_part [4][64][5] f32
    __shared__ __align__(16) unsigned short fd_lds[64 * 256]; // 32KB, granule-swizzled [edge][c16^(edge&7)]
    __shared__ unsigned short wb1t[NB_ * 256];           // 2.5KB bf16, [b][m]
    __shared__ float dw[64];
    __shared__ int li_s[64], lj_s[64];

    unsigned short* esym_lds  = (unsigned short*)smem0;
    float*          bonds_part = (float*)smem0;

    const int tid = threadIdx.x;
    const int blk = blockIdx.x;
    const int l   = tid & 63;
    const int w   = tid >> 6;
    const int eLo = l & 15;
    const int hi  = l >> 4;

    // ---- stage W_b1^T (bf16) into LDS
    {
        #pragma unroll
        for (int b = 0; b < NB_; ++b)
            wb1t[b * 256 + tid] = f2bf(W_b1[(size_t)tid * NB_ + b]);
    }

    // ---- meta (wave 0 publishes) + e gather/symmetrize into B-frag LDS layout
    {
        const int eL = l;          // edge-local 0..63
        const int q  = w;          // k-chunk 0..3 (32 k each)
        int ge = blk * 64 + eL;
        int j  = ei[ge], i2 = ei[NE_ + ge];
        int k1 = emap[j * N_NODES + i2];
        int k2 = emap[i2 * N_NODES + j];
        if (w == 0) {
            li_s[eL] = i2; lj_s[eL] = j;
            float dx = coords[i2 * 3 + 0] - coords[j * 3 + 0];
            float dy = coords[i2 * 3 + 1] - coords[j * 3 + 1];
            float dz = coords[i2 * 3 + 2] - coords[j * 3 + 2];
            dw[eL] = dx * dx + dy * dy + dz * dz;
        }
        const float4* p1 = (const float4*)(e + (size_t)k1 * ED_ + q * 32);
        float4 va[8];
        #pragma unroll
        for (int t = 0; t < 8; ++t) va[t] = p1[t];
        if (k2 >= 0) {
            const float4* p2 = (const float4*)(e + (size_t)k2 * ED_ + q * 32);
            #pragma unroll
            for (int t = 0; t < 8; ++t) {
                float4 b4 = p2[t];
                va[t].x += b4.x; va[t].y += b4.y; va[t].z += b4.z; va[t].w += b4.w;
            }
        }
        int ntB = eL >> 4, eLoB = eL & 15;
        #pragma unroll
        for (int h2 = 0; h2 < 4; ++h2) {
            float4 x0 = va[h2 * 2], x1 = va[h2 * 2 + 1];
            uint4 c;
            c.x = cvt_pk_bf16(0.5f * x0.x, 0.5f * x0.y);
            c.y = cvt_pk_bf16(0.5f * x0.z, 0.5f * x0.w);
            c.z = cvt_pk_bf16(0.5f * x1.x, 0.5f * x1.y);
            c.w = cvt_pk_bf16(0.5f * x1.z, 0.5f * x1.w);
            // lane-linear within a wave: chunk % 8 == eL % 8 -> 2-way max (free)
            int chunk = (ntB * 4 + q) * 64 + h2 * 16 + eLoB;
            *(uint4*)(&esym_lds[chunk * 8]) = c;
        }
    }

    // prefetch GEMM1 kb=0 A-frags (independent of LDS; hides L2 latency under barrier)
    bf16x8 a1p[4];
    #pragma unroll
    for (int mt = 0; mt < 4; ++mt)
        a1p[mt] = *(const bf16x8*)(WfA_bm + ((size_t)(((w * 4 + mt) * 4 + 0) * 64 + l) * 8));

    __syncthreads();   // bar1: esym + meta + wb1t ready

    // ---- GEMM1': K=128 (4 k-steps)
    f32x4 acc[4][4];
    #pragma unroll
    for (int mt = 0; mt < 4; ++mt)
        #pragma unroll
        for (int nt = 0; nt < 4; ++nt) acc[mt][nt] = (f32x4){0.f, 0.f, 0.f, 0.f};

    #pragma unroll
    for (int kb = 0; kb < 4; ++kb) {
        bf16x8 af[4], bfg[4];
        #pragma unroll
        for (int mt = 0; mt < 4; ++mt)
            af[mt] = (kb == 0) ? a1p[mt]
                   : *(const bf16x8*)(WfA_bm + ((size_t)(((w * 4 + mt) * 4 + kb) * 64 + l) * 8));
        #pragma unroll
        for (int nt = 0; nt < 4; ++nt)
            bfg[nt] = *(const bf16x8*)(&esym_lds[(size_t)((nt * 4 + kb) * 64 + l) * 8]);
        __builtin_amdgcn_s_setprio(1);
        #pragma unroll
        for (int mt = 0; mt < 4; ++mt)
            #pragma unroll
            for (int nt = 0; nt < 4; ++nt)
                acc[mt][nt] = __builtin_amdgcn_mfma_f32_16x16x32_bf16(af[mt], bfg[nt], acc[mt][nt], 0, 0, 0);
        __builtin_amdgcn_s_setprio(0);
    }

    // prefetch GEMM2 kb=0 A-frags before the epilogue (T14 issue-early)
    bf16x8 a2p[4];
    #pragma unroll
    for (int mt = 0; mt < 4; ++mt)
        a2p[mt] = *(const bf16x8*)(WfA_b0 + ((size_t)(((w * 4 + mt) * 8 + 0) * 64 + l) * 8));

    // ---- epilogue 1: f = acc + s_i + s_j + b_bm -> swizzled fd (bf16)
    #pragma unroll
    for (int mt = 0; mt < 4; ++mt) {
        int m0 = w * 64 + mt * 16 + hi * 4;
        float4 bb = *(const float4*)(b_bm + m0);
        #pragma unroll
        for (int nt = 0; nt < 4; ++nt) {
            int edge = nt * 16 + eLo;
            int ni = li_s[edge], nj = lj_s[edge];
            ushort4 si = *(const ushort4*)(s2b + (size_t)ni * SD_ + m0);
            ushort4 sj = *(const ushort4*)(s2b + (size_t)nj * SD_ + m0);
            f32x4 r = acc[mt][nt];
            float f0 = r[0] + bf2f(si.x) + bf2f(sj.x) + bb.x;
            float f1 = r[1] + bf2f(si.y) + bf2f(sj.y) + bb.y;
            float f2 = r[2] + bf2f(si.z) + bf2f(sj.z) + bb.z;
            float f3 = r[3] + bf2f(si.w) + bf2f(sj.w) + bb.w;
            uint2 pk;
            pk.x = cvt_pk_bf16(f0, f1);
            pk.y = cvt_pk_bf16(f2, f3);
            int c16 = m0 >> 3;                       // 16B granule index 0..31
            int byteo = (edge << 9) + ((c16 ^ (edge & 7)) << 4) + ((m0 & 7) << 1);
            *(uint2*)((char*)fd_lds + byteo) = pk;
        }
    }
    __syncthreads();   // bar2: fd ready

    // ---- GEMM2': K=256 (8 k-steps); init = b_b0 + d * W_b0[row 256]
    #pragma unroll
    for (int mt = 0; mt < 4; ++mt) {
        int m0 = w * 64 + mt * 16 + hi * 4;
        float4 b0 = *(const float4*)(b_b0 + m0);
        float4 w2 = *(const float4*)(W_b0_last + m0);
        #pragma unroll
        for (int nt = 0; nt < 4; ++nt) {
            float dd = dw[nt * 16 + eLo];
            acc[mt][nt] = (f32x4){fmaf(dd, w2.x, b0.x), fmaf(dd, w2.y, b0.y),
                                  fmaf(dd, w2.z, b0.z), fmaf(dd, w2.w, b0.w)};
        }
    }
    #pragma unroll
    for (int kb = 0; kb < 8; ++kb) {
        bf16x8 af[4], bfg[4];
        #pragma unroll
        for (int mt = 0; mt < 4; ++mt)
            af[mt] = (kb == 0) ? a2p[mt]
                   : *(const bf16x8*)(WfA_b0 + ((size_t)(((w * 4 + mt) * 8 + kb) * 64 + l) * 8));
        #pragma unroll
        for (int nt = 0; nt < 4; ++nt) {
            int edge = nt * 16 + eLo;
            int c16 = (kb << 2) + hi;
            int byteo = (edge << 9) + ((c16 ^ (edge & 7)) << 4);
            bfg[nt] = *(const bf16x8*)((const char*)fd_lds + byteo);
        }
        __builtin_amdgcn_s_setprio(1);
        #pragma unroll
        for (int mt = 0; mt < 4; ++mt)
            #pragma unroll
            for (int nt = 0; nt < 4; ++nt)
                acc[mt][nt] = __builtin_amdgcn_mfma_f32_16x16x32_bf16(af[mt], bfg[nt], acc[mt][nt], 0, 0, 0);
        __builtin_amdgcn_s_setprio(0);
    }

    // ---- bonds: h = silu(pre) fp32, dot with W_b1 (bf16), reduce over m
    float pb[4][NB_];
    #pragma unroll
    for (int nt = 0; nt < 4; ++nt)
        #pragma unroll
        for (int b = 0; b < NB_; ++b) pb[nt][b] = 0.f;
    #pragma unroll
    for (int mt = 0; mt < 4; ++mt) {
        int m0 = w * 64 + mt * 16 + hi * 4;
        ushort4 wv[NB_];
        #pragma unroll
        for (int b = 0; b < NB_; ++b)
            wv[b] = *(const ushort4*)(wb1t + b * 256 + m0);   // broadcast across eLo lanes
        #pragma unroll
        for (int nt = 0; nt < 4; ++nt) {
            f32x4 r = acc[mt][nt];
            float h0 = silu_fast(r[0]);
            float h1 = silu_fast(r[1]);
            float h2 = silu_fast(r[2]);
            float h3 = silu_fast(r[3]);
            #pragma unroll
            for (int b = 0; b < NB_; ++b) {
                float t = fmaf(h0, bf2f(wv[b].x), fmaf(h1, bf2f(wv[b].y),
                          fmaf(h2, bf2f(wv[b].z), h3 * bf2f(wv[b].w))));
                pb[nt][b] += t;
            }
        }
    }
    // reduce over hi groups (lanes l, l^16, l^32, l^48 share the same edge column)
    #pragma unroll
    for (int off = 16; off <= 32; off <<= 1)
        #pragma unroll
        for (int nt = 0; nt < 4; ++nt)
            #pragma unroll
            for (int b = 0; b < NB_; ++b)
                pb[nt][b] += __shfl_xor(pb[nt][b], off);
    if (hi == 0) {
        #pragma unroll
        for (int nt = 0; nt < 4; ++nt)
            #pragma unroll
            for (int b = 0; b < NB_; ++b)
                bonds_part[(size_t)(w * 64 + nt * 16 + eLo) * NB_ + b] = pb[nt][b];
    }
    __syncthreads();   // bar3

    // 320 (edge,b) pairs, 256 threads -> strided loop (R3 bug: `if (tid<320)` dropped 64)
    for (int idx = tid; idx < 64 * NB_; idx += 256) {
        int edge = idx / NB_, b = idx % NB_;
        float s4 = bonds_part[(size_t)(0 * 64 + edge) * NB_ + b]
                 + bonds_part[(size_t)(1 * 64 + edge) * NB_ + b]
                 + bonds_part[(size_t)(2 * 64 + edge) * NB_ + b]
                 + bonds_part[(size_t)(3 * 64 + edge) * NB_ + b];
        bonds_out[(size_t)(blk * 64 + edge) * NB_ + b] = s4 + b_b1[b];
    }
}

extern "C" void kernel_launch(void* const* d_in, const int* in_sizes, int n_in,
                              void* d_out, int out_size, void* d_ws, size_t ws_size,
                              hipStream_t stream)
{
    const float* s    = (const float*)d_in[0];
    const float* v    = (const float*)d_in[1];
    const float* p    = (const float*)d_in[2];
    const float* e    = (const float*)d_in[3];
    const int*   batch= (const int*)d_in[4];
    const int*   ei   = (const int*)d_in[5];
    const float* W_sm = (const float*)d_in[6];
    const float* b_sm = (const float*)d_in[7];
    const float* W_bm = (const float*)d_in[8];
    const float* b_bm = (const float*)d_in[9];
    const float* W_b0 = (const float*)d_in[10];
    const float* b_b0 = (const float*)d_in[11];
    const float* W_b1 = (const float*)d_in[12];
    const float* b_b1 = (const float*)d_in[13];
    const float* W_c  = (const float*)d_in[14];
    const float* W_a  = (const float*)d_in[15];
    const float* b_a  = (const float*)d_in[16];

    float* out = (float*)d_out;
    float* coords_out = out;                       // 512*3
    float* atoms_out  = out + 1536;                // 512*16
    float* bonds_out  = out + 1536 + 8192;         // 262144*5

    char* ws = (char*)d_ws;
    int*            emap    = (int*)ws;                                  // @0, 1 MB
    unsigned short* s2b     = (unsigned short*)(ws + 0x100000);          // 256 KB
    unsigned short* WfA_bm  = (unsigned short*)(ws + 0x140000);          // 64 KB
    unsigned short* WfA_b0  = (unsigned short*)(ws + 0x150000);          // 128 KB
    float*          cpred   = (float*)(ws + 0x170000);                   // 6 KB
    float*          coords  = (float*)(ws + 0x172000);                   // 6 KB

    hipMemsetAsync(emap, 0xFF, N_NODES * N_NODES * sizeof(int), stream); // emap = -1

    build_and_pack<<<NE_ / 256 + 48, 256, 0, stream>>>(ei, emap, W_bm, W_b0, WfA_bm, WfA_b0);
    node_kernel8<<<N_NODES / 8, 256, 0, stream>>>(s, v, p, W_sm, b_sm, W_a, b_a, W_c,
                                                  s2b, cpred, atoms_out);
    center_kernel<<<1, 512, 0, stream>>>(cpred, batch, coords, coords_out);

    edge_mfma<<<NE_ / 64, 256, 0, stream>>>(e, ei, emap, coords, s2b,
                                            WfA_bm, WfA_b0, W_b1,
                                            b_bm, W_b0 + 256 * SD_, b_b0, b_b1,
                                            bonds_out);
}